// Round 1
// baseline (2844.001 us; speedup 1.0000x reference)
//
#include <hip/hip_runtime.h>

// Problem constants (match reference)
#define SEQ 2048
#define BAT 256
#define KD  64
#define HD  128

// ---------------------------------------------------------------------------
// Kernel 1: precompute type-dependent tables into d_ws.
//   tabH[ty][r] = sum_k embed_W[ty][k]*W_ih[r][k] + b_ih[r] + b_hh[r]
//   tabD[ty][r] = sum_k embed_W[ty][k]*dec_W[r][k] + dec_b[r]
// ---------------------------------------------------------------------------
__global__ __launch_bounds__(128) void precompute_tables(
    const float* __restrict__ embed_W, const float* __restrict__ W_ih,
    const float* __restrict__ b_ih,    const float* __restrict__ b_hh,
    const float* __restrict__ dec_W,   const float* __restrict__ dec_b,
    float* __restrict__ tabH, float* __restrict__ tabD)
{
    __shared__ float x[KD];
    const int ty = blockIdx.x;   // 0..64 (row 64 = padding, embed row is zero)
    const int r  = threadIdx.x;  // 0..127
    if (r < KD) x[r] = embed_W[ty * KD + r];
    __syncthreads();
    float ah = 0.f, ad = 0.f;
#pragma unroll
    for (int k = 0; k < KD; ++k) {
        const float xv = x[k];
        ah += xv * W_ih[r * KD + k];
        ad += xv * dec_W[r * (KD + HD) + k];
    }
    tabH[ty * HD + r] = ah + b_ih[r] + b_hh[r];
    tabD[ty * HD + r] = ad + dec_b[r];
}

// ---------------------------------------------------------------------------
// Kernel 2: persistent per-batch-element recurrence.
// One workgroup per batch element b. 512 threads = 8 waves.
// Row r in [0,128) owned by a 4-lane quad:
//   role 0: hidden dot, j=0..63      role 1: hidden dot, j=64..127
//   role 2: decay  dot, j=0..63      role 3: decay  dot, j=64..127
// Each lane holds 64 f32 weights in registers. h state double-buffered in LDS,
// one barrier per step.
// ---------------------------------------------------------------------------
__global__ __launch_bounds__(512, 2) void hawkes_rnn(
    const float* __restrict__ dt_g,  const float* __restrict__ h0,
    const float* __restrict__ W_hh,  const float* __restrict__ dec_W,
    const int*   __restrict__ seq_types,
    const float* __restrict__ tabH,  const float* __restrict__ tabD,
    float* __restrict__ out)
{
    __shared__ __align__(16) float hbuf[2][HD];
    __shared__ float dts[SEQ];
    __shared__ int   tys[SEQ];

    const int b    = blockIdx.x;
    const int tid  = threadIdx.x;
    const int wave = tid >> 6;
    const int lane = tid & 63;
    const int i    = lane >> 2;
    const int role = lane & 3;
    const int r    = wave * 16 + i;          // output row
    const int j_off = (role & 1) * 64;       // which half of h this lane dots

    // Stage dt / seq_types columns for this batch element.
    for (int t = tid; t < SEQ; t += 512) {
        dts[t] = dt_g[(size_t)t * BAT + b];
        tys[t] = seq_types[(size_t)t * BAT + b];
    }
    if (tid < HD) hbuf[0][tid] = h0[b * HD + tid];

    // Load this lane's 64 weights into registers (statically indexed).
    const float* wrow = (role < 2) ? (W_hh  + r * HD + j_off)
                                   : (dec_W + r * (KD + HD) + KD + j_off);
    float w[64];
#pragma unroll
    for (int q = 0; q < 16; ++q) {
        const float4 v = *reinterpret_cast<const float4*>(wrow + q * 4);
        w[q * 4 + 0] = v.x; w[q * 4 + 1] = v.y;
        w[q * 4 + 2] = v.z; w[q * 4 + 3] = v.w;
    }
    // Per-lane table column pointer (roles 0/1 -> tabH, 2/3 -> tabD).
    const float* tab = (((role & 2) ? tabD : tabH)) + r;

    __syncthreads();

    float* o_hid = out;
    float* o_dec = out + (size_t)SEQ * BAT * HD;
    float* o_hti = out + (size_t)2 * SEQ * BAT * HD;

    // Table prefetch pipeline (2 steps ahead; tables are L2-resident).
    float tab_cur = tab[tys[0] * HD];
    float tab_nxt = tab[tys[1] * HD];
    int p = 0;

    for (int t = 0; t < SEQ; ++t) {
        const int   tpf    = (t + 2 < SEQ) ? tys[t + 2] : 0;
        const float tab_pf = tab[tpf * HD];     // issue load now, use at t+2
        const float dtv    = dts[t];
        const float* hb    = hbuf[p];

        float a0 = 0.f, a1 = 0.f, a2 = 0.f, a3 = 0.f;
#pragma unroll
        for (int q = 0; q < 16; ++q) {
            const float4 hv = *reinterpret_cast<const float4*>(hb + j_off + q * 4);
            a0 += w[q * 4 + 0] * hv.x;
            a1 += w[q * 4 + 1] * hv.y;
            a2 += w[q * 4 + 2] * hv.z;
            a3 += w[q * 4 + 3] * hv.w;
        }
        float acc = (a0 + a1) + (a2 + a3);
        if ((role & 1) == 0) acc += tab_cur;    // add table term once per dot

        // Combine half-dots within the pair: roles 0,1 -> full hidden preact,
        // roles 2,3 -> full decay preact.
        const float s = acc + __shfl_xor(acc, 1);

        // softplus10 (stable, matches jax.nn.softplus(10x)/10)
        const float z  = 10.f * s;
        const float sp = (fmaxf(z, 0.f) + log1pf(__expf(-fabsf(z)))) * 0.1f;
        // roles 0,1 produce hidden=tanh(s); roles 2,3 produce e=exp(-decay*dt)
        const float v = (role & 2) ? __expf(-sp * dtv) : tanhf(s);
        // swap hidden <-> e across the quad; hnew = hidden * e on all lanes
        const float cross = __shfl_xor(v, 2);
        const float hnew  = v * cross;

        const size_t ofs = (size_t)t * (BAT * HD) + (size_t)b * HD + r;
        if (role == 0) {
            o_hid[ofs] = v;          // hidden
            o_hti[ofs] = hnew;       // decayed hidden (next state)
            hbuf[p ^ 1][r] = hnew;
        } else if (role == 2) {
            o_dec[ofs] = sp;         // decay
        }

        tab_cur = tab_nxt;
        tab_nxt = tab_pf;
        __syncthreads();             // h(t+1) visible to all before next step
        p ^= 1;
    }
}

extern "C" void kernel_launch(void* const* d_in, const int* in_sizes, int n_in,
                              void* d_out, int out_size, void* d_ws, size_t ws_size,
                              hipStream_t stream) {
    const float* dt        = (const float*)d_in[0];
    const float* h0        = (const float*)d_in[1];
    const float* embed_W   = (const float*)d_in[2];
    const float* W_ih      = (const float*)d_in[3];
    const float* b_ih      = (const float*)d_in[4];
    const float* W_hh      = (const float*)d_in[5];
    const float* b_hh      = (const float*)d_in[6];
    const float* dec_W     = (const float*)d_in[7];
    const float* dec_b     = (const float*)d_in[8];
    const int*   seq_types = (const int*)  d_in[9];
    float* out  = (float*)d_out;

    float* tabH = (float*)d_ws;                 // [65][128]
    float* tabD = tabH + (KD + 1) * HD;         // [65][128]  (66,560 B total)

    precompute_tables<<<KD + 1, 128, 0, stream>>>(embed_W, W_ih, b_ih, b_hh,
                                                  dec_W, dec_b, tabH, tabD);
    hawkes_rnn<<<BAT, 512, 0, stream>>>(dt, h0, W_hh, dec_W, seq_types,
                                        tabH, tabD, out);
}

// Round 2
// 1658.107 us; speedup vs baseline: 1.7152x; 1.7152x over previous
//
#include <hip/hip_runtime.h>

// Problem constants (match reference)
#define SEQ 2048
#define BAT 256
#define KD  64
#define HD  128
#define PADW 24   // 16 payload floats + 8 pad -> chunk stride 96B (16B-aligned, 2-way bank alias = free)

// ---------------------------------------------------------------------------
// Kernel 1: precompute type-dependent tables into d_ws.
//   tabH[ty][r] = sum_k embed_W[ty][k]*W_ih[r][k] + b_ih[r] + b_hh[r]
//   tabD[ty][r] = sum_k embed_W[ty][k]*dec_W[r][k] + dec_b[r]
// ---------------------------------------------------------------------------
__global__ __launch_bounds__(128) void precompute_tables(
    const float* __restrict__ embed_W, const float* __restrict__ W_ih,
    const float* __restrict__ b_ih,    const float* __restrict__ b_hh,
    const float* __restrict__ dec_W,   const float* __restrict__ dec_b,
    float* __restrict__ tabH, float* __restrict__ tabD)
{
    __shared__ float x[KD];
    const int ty = blockIdx.x;   // 0..64 (row 64 = padding, embed row is zero)
    const int r  = threadIdx.x;  // 0..127
    if (r < KD) x[r] = embed_W[ty * KD + r];
    __syncthreads();
    float ah = 0.f, ad = 0.f;
#pragma unroll
    for (int k = 0; k < KD; ++k) {
        const float xv = x[k];
        ah += xv * W_ih[r * KD + k];
        ad += xv * dec_W[r * (KD + HD) + k];
    }
    tabH[ty * HD + r] = ah + b_ih[r] + b_hh[r];
    tabD[ty * HD + r] = ad + dec_b[r];
}

// ---------------------------------------------------------------------------
// Kernel 2: persistent per-batch-element recurrence. One workgroup per batch
// element, 512 threads = 8 waves. Thread decomposition per step:
//   c = tid & 7        : column chunk (16 h-values each, 4x ds_read_b128)
//   f = (tid>>3) & 1   : 0 = hidden matvec (W_hh), 1 = decay matvec (dec_W)
//   g = tid >> 4       : row group (4 consecutive output rows)
// Each lane: 64 register weights, 64 FMAs, butterfly-reduce over the 8 chunk
// lanes (shfl_xor 1/2/4), hidden<->decay exchange via shfl_xor 8.
// h double-buffered in padded LDS; ONE barrier per step.
// ---------------------------------------------------------------------------
__global__ __launch_bounds__(512) void hawkes_rnn(
    const float* __restrict__ dt_g,  const float* __restrict__ h0,
    const float* __restrict__ W_hh,  const float* __restrict__ dec_W,
    const int*   __restrict__ seq_types,
    const float* __restrict__ tabH,  const float* __restrict__ tabD,
    float* __restrict__ out)
{
    __shared__ __align__(16) float hpad[2][8][PADW];
    __shared__ float dts[SEQ];
    __shared__ int   tys[SEQ];

    const int b   = blockIdx.x;
    const int tid = threadIdx.x;
    const int c   = tid & 7;          // chunk
    const int f   = (tid >> 3) & 1;   // function
    const int g   = tid >> 4;         // row group, 0..31
    const int row = 4 * g + (c & 3);  // the row this lane finalizes (c>=4 dup)

    // Stage dt / seq_types columns for this batch element.
    for (int t = tid; t < SEQ; t += 512) {
        dts[t] = dt_g[(size_t)t * BAT + b];
        tys[t] = seq_types[(size_t)t * BAT + b];
    }
    if (tid < HD) hpad[0][tid >> 4][tid & 15] = h0[b * HD + tid];

    // Load this lane's 4x16 weight block into registers (statically indexed).
    float4 wv[4][4];
#pragma unroll
    for (int rr = 0; rr < 4; ++rr) {
        const int r = 4 * g + rr;
        const float* wrow = f ? (dec_W + (size_t)r * (KD + HD) + KD + c * 16)
                              : (W_hh  + (size_t)r * HD + c * 16);
#pragma unroll
        for (int q = 0; q < 4; ++q)
            wv[rr][q] = *reinterpret_cast<const float4*>(wrow + q * 4);
    }
    const float* tabp = (f ? tabD : tabH) + row;

    __syncthreads();

    float* o_hid = out;
    float* o_dec = out + (size_t)SEQ * BAT * HD;
    float* o_hti = out + (size_t)2 * SEQ * BAT * HD;

    // Table prefetch pipeline (2 steps ahead; tables are L2-resident).
    float tab_cur = tabp[tys[0] * HD];
    float tab_nxt = tabp[tys[1] * HD];
    int p = 0;

    for (int t = 0; t < SEQ; ++t) {
        const int   tpf    = (t + 2 < SEQ) ? tys[t + 2] : 0;
        const float tab_pf = tabp[tpf * HD];   // issue now, use at t+2
        const float dtv    = dts[t];
        const float* hb    = &hpad[p][c][0];

        float s0 = 0.f, s1 = 0.f, s2 = 0.f, s3 = 0.f;
#pragma unroll
        for (int q = 0; q < 4; ++q) {
            const float4 hv = *reinterpret_cast<const float4*>(hb + q * 4);
            s0 = fmaf(wv[0][q].x, hv.x, s0); s0 = fmaf(wv[0][q].y, hv.y, s0);
            s0 = fmaf(wv[0][q].z, hv.z, s0); s0 = fmaf(wv[0][q].w, hv.w, s0);
            s1 = fmaf(wv[1][q].x, hv.x, s1); s1 = fmaf(wv[1][q].y, hv.y, s1);
            s1 = fmaf(wv[1][q].z, hv.z, s1); s1 = fmaf(wv[1][q].w, hv.w, s1);
            s2 = fmaf(wv[2][q].x, hv.x, s2); s2 = fmaf(wv[2][q].y, hv.y, s2);
            s2 = fmaf(wv[2][q].z, hv.z, s2); s2 = fmaf(wv[2][q].w, hv.w, s2);
            s3 = fmaf(wv[3][q].x, hv.x, s3); s3 = fmaf(wv[3][q].y, hv.y, s3);
            s3 = fmaf(wv[3][q].z, hv.z, s3); s3 = fmaf(wv[3][q].w, hv.w, s3);
        }
        // Butterfly reduce across the 8 chunk lanes (lane bits 0..2).
#pragma unroll
        for (int m = 1; m <= 4; m <<= 1) {
            s0 += __shfl_xor(s0, m);
            s1 += __shfl_xor(s1, m);
            s2 += __shfl_xor(s2, m);
            s3 += __shfl_xor(s3, m);
        }
        const int cs = c & 3;
        float sv = (cs == 0) ? s0 : (cs == 1) ? s1 : (cs == 2) ? s2 : s3;
        sv += tab_cur;

        float v, sp = 0.f;
        if (f == 0) {
            // tanh(sv) = 1 - 2/(exp(2sv)+1); exp->inf and ->0 both safe.
            const float e2 = __expf(2.f * sv);
            v = 1.f - __fdividef(2.f, e2 + 1.f);
        } else {
            // softplus10 + decay factor
            const float z  = 10.f * sv;
            const float em = __expf(-fabsf(z));
            sp = 0.1f * (fmaxf(z, 0.f) + __logf(1.f + em));
            v  = __expf(-sp * dtv);
        }
        const float cross = __shfl_xor(v, 8);   // swap hidden <-> decay-factor
        const float hnew  = v * cross;

        if (c < 4) {
            const size_t ofs = (size_t)t * (BAT * HD) + (size_t)b * HD + row;
            if (f == 0) {
                o_hid[ofs] = v;
                o_hti[ofs] = hnew;
                hpad[p ^ 1][row >> 4][row & 15] = hnew;
            } else {
                o_dec[ofs] = sp;
            }
        }

        tab_cur = tab_nxt;
        tab_nxt = tab_pf;
        __syncthreads();
        p ^= 1;
    }
}

extern "C" void kernel_launch(void* const* d_in, const int* in_sizes, int n_in,
                              void* d_out, int out_size, void* d_ws, size_t ws_size,
                              hipStream_t stream) {
    const float* dt        = (const float*)d_in[0];
    const float* h0        = (const float*)d_in[1];
    const float* embed_W   = (const float*)d_in[2];
    const float* W_ih      = (const float*)d_in[3];
    const float* b_ih      = (const float*)d_in[4];
    const float* W_hh      = (const float*)d_in[5];
    const float* b_hh      = (const float*)d_in[6];
    const float* dec_W     = (const float*)d_in[7];
    const float* dec_b     = (const float*)d_in[8];
    const int*   seq_types = (const int*)  d_in[9];
    float* out  = (float*)d_out;

    float* tabH = (float*)d_ws;                 // [65][128]
    float* tabD = tabH + (KD + 1) * HD;         // [65][128]

    precompute_tables<<<KD + 1, 128, 0, stream>>>(embed_W, W_ih, b_ih, b_hh,
                                                  dec_W, dec_b, tabH, tabD);
    hawkes_rnn<<<BAT, 512, 0, stream>>>(dt, h0, W_hh, dec_W, seq_types,
                                        tabH, tabD, out);
}

// Round 4
// 1309.643 us; speedup vs baseline: 2.1716x; 1.2661x over previous
//
#include <hip/hip_runtime.h>

// Problem constants (match reference)
#define SEQ 2048
#define BAT 256
#define KD  64
#define HD  128
#define PADW 24   // 16 payload floats + 8 pad -> chunk stride 96B

// ds_swizzle xor patterns (BitMode: (xor<<10)|(or<<5)|and, and=0x1F)
template<int PAT>
__device__ __forceinline__ float swz(float x) {
    return __int_as_float(__builtin_amdgcn_ds_swizzle(__float_as_int(x), PAT));
}
#define XOR1 0x041F
#define XOR2 0x081F
#define XOR4 0x101F
#define XOR8 0x201F

// Pin a scalar float into a VGPR: load can't sink past the volatile asm,
// value becomes opaque so it stays register-resident across the loop.
// (float4 "+v" ties are unsupported: "tied indirect register inputs".)
#define PIN(x) asm volatile("" : "+v"(x))
#define PIN4(v4) PIN(v4.x); PIN(v4.y); PIN(v4.z); PIN(v4.w)

// ---------------------------------------------------------------------------
// Kernel 1: precompute type-dependent tables into d_ws.
//   tabH[ty][r] = sum_k embed_W[ty][k]*W_ih[r][k] + b_ih[r] + b_hh[r]
//   tabD[ty][r] = sum_k embed_W[ty][k]*dec_W[r][k] + dec_b[r]
// ---------------------------------------------------------------------------
__global__ __launch_bounds__(128) void precompute_tables(
    const float* __restrict__ embed_W, const float* __restrict__ W_ih,
    const float* __restrict__ b_ih,    const float* __restrict__ b_hh,
    const float* __restrict__ dec_W,   const float* __restrict__ dec_b,
    float* __restrict__ tabH, float* __restrict__ tabD)
{
    __shared__ float x[KD];
    const int ty = blockIdx.x;   // 0..64 (row 64 = padding, embed row is zero)
    const int r  = threadIdx.x;  // 0..127
    if (r < KD) x[r] = embed_W[ty * KD + r];
    __syncthreads();
    float ah = 0.f, ad = 0.f;
#pragma unroll
    for (int k = 0; k < KD; ++k) {
        const float xv = x[k];
        ah += xv * W_ih[r * KD + k];
        ad += xv * dec_W[r * (KD + HD) + k];
    }
    tabH[ty * HD + r] = ah + b_ih[r] + b_hh[r];
    tabD[ty * HD + r] = ad + dec_b[r];
}

// ---------------------------------------------------------------------------
// Kernel 2: persistent per-batch-element recurrence. One workgroup per batch
// element, 512 threads = 8 waves. Thread decomposition per step:
//   c = tid & 7        : column chunk (16 h-values each, 4x ds_read_b128)
//   f = (tid>>3) & 1   : 0 = hidden matvec (W_hh), 1 = decay matvec (dec_W)
//   g = tid >> 4       : row group (4 consecutive output rows)
// Each lane holds its 4x16 weight block in 16 float4 REGISTERS, pinned via
// scalar asm volatile so the compiler cannot sink the loads into the loop
// (round-1 failure mode: VGPR=48 + FETCH=17 GB -> weights re-fetched from L2
// every step, L2-BW-bound at ~39 TB/s).
// Reduction over the 8 chunk lanes: value-halving butterfly, 4 ds_swizzles.
// Row finalized by lane c (c<4): row = 4g + ((c&1)<<1 | (c>>1)&1).
// h double-buffered in padded LDS; ONE barrier per step.
// ---------------------------------------------------------------------------
__global__ __launch_bounds__(512, 2) void hawkes_rnn(
    const float* __restrict__ dt_g,  const float* __restrict__ h0,
    const float* __restrict__ W_hh,  const float* __restrict__ dec_W,
    const int*   __restrict__ seq_types,
    const float* __restrict__ tabH,  const float* __restrict__ tabD,
    float* __restrict__ out)
{
    __shared__ __align__(16) float hpad[2][8][PADW];
    __shared__ float dts[SEQ];
    __shared__ int   tys[SEQ];

    const int b   = blockIdx.x;
    const int tid = threadIdx.x;
    const int c   = tid & 7;          // chunk
    const int f   = (tid >> 3) & 1;   // function
    const int g   = tid >> 4;         // row group, 0..31
    const int rsel = ((c & 1) << 1) | ((c >> 1) & 1);  // bit-swap from butterfly
    const int row  = 4 * g + rsel;    // the row this lane finalizes (c>=4 dup)

    // Stage dt / seq_types columns for this batch element.
    for (int t = tid; t < SEQ; t += 512) {
        dts[t] = dt_g[(size_t)t * BAT + b];
        tys[t] = seq_types[(size_t)t * BAT + b];
    }
    if (tid < HD) hpad[0][tid >> 4][tid & 15] = h0[b * HD + tid];

    // Load this lane's 4x16 weight block into NAMED registers and pin them.
    const float* wbase = f ? (dec_W + KD + (size_t)(4 * g) * (KD + HD) + c * 16)
                           : (W_hh  +      (size_t)(4 * g) * HD        + c * 16);
    const size_t wstr = f ? (KD + HD) : HD;
    float4 w00 = *reinterpret_cast<const float4*>(wbase + 0 * wstr + 0);
    float4 w01 = *reinterpret_cast<const float4*>(wbase + 0 * wstr + 4);
    float4 w02 = *reinterpret_cast<const float4*>(wbase + 0 * wstr + 8);
    float4 w03 = *reinterpret_cast<const float4*>(wbase + 0 * wstr + 12);
    float4 w10 = *reinterpret_cast<const float4*>(wbase + 1 * wstr + 0);
    float4 w11 = *reinterpret_cast<const float4*>(wbase + 1 * wstr + 4);
    float4 w12 = *reinterpret_cast<const float4*>(wbase + 1 * wstr + 8);
    float4 w13 = *reinterpret_cast<const float4*>(wbase + 1 * wstr + 12);
    float4 w20 = *reinterpret_cast<const float4*>(wbase + 2 * wstr + 0);
    float4 w21 = *reinterpret_cast<const float4*>(wbase + 2 * wstr + 4);
    float4 w22 = *reinterpret_cast<const float4*>(wbase + 2 * wstr + 8);
    float4 w23 = *reinterpret_cast<const float4*>(wbase + 2 * wstr + 12);
    float4 w30 = *reinterpret_cast<const float4*>(wbase + 3 * wstr + 0);
    float4 w31 = *reinterpret_cast<const float4*>(wbase + 3 * wstr + 4);
    float4 w32 = *reinterpret_cast<const float4*>(wbase + 3 * wstr + 8);
    float4 w33 = *reinterpret_cast<const float4*>(wbase + 3 * wstr + 12);
    PIN4(w00); PIN4(w01); PIN4(w02); PIN4(w03);
    PIN4(w10); PIN4(w11); PIN4(w12); PIN4(w13);
    PIN4(w20); PIN4(w21); PIN4(w22); PIN4(w23);
    PIN4(w30); PIN4(w31); PIN4(w32); PIN4(w33);

    const float* tabp = (f ? tabD : tabH) + row;

    __syncthreads();

    float* o_hid = out;
    float* o_dec = out + (size_t)SEQ * BAT * HD;
    float* o_hti = out + (size_t)2 * SEQ * BAT * HD;

    // Table prefetch pipeline (2 steps ahead; tables are L2-resident).
    float tab_cur = tabp[tys[0] * HD];
    float tab_nxt = tabp[tys[1] * HD];
    int p = 0;

    for (int t = 0; t < SEQ; ++t) {
        const int   tpf    = (t + 2 < SEQ) ? tys[t + 2] : 0;
        const float tab_pf = tabp[tpf * HD];   // issue now, use at t+2
        const float dtv    = dts[t];
        const float* hb    = &hpad[p][c][0];

        const float4 h0v = *reinterpret_cast<const float4*>(hb + 0);
        const float4 h1v = *reinterpret_cast<const float4*>(hb + 4);
        const float4 h2v = *reinterpret_cast<const float4*>(hb + 8);
        const float4 h3v = *reinterpret_cast<const float4*>(hb + 12);

        float s0 = 0.f, s1 = 0.f, s2 = 0.f, s3 = 0.f;
#define ACC(W0,W1,W2,W3,HV) \
        s0 = fmaf(W0.x, HV.x, s0); s0 = fmaf(W0.y, HV.y, s0); \
        s0 = fmaf(W0.z, HV.z, s0); s0 = fmaf(W0.w, HV.w, s0); \
        s1 = fmaf(W1.x, HV.x, s1); s1 = fmaf(W1.y, HV.y, s1); \
        s1 = fmaf(W1.z, HV.z, s1); s1 = fmaf(W1.w, HV.w, s1); \
        s2 = fmaf(W2.x, HV.x, s2); s2 = fmaf(W2.y, HV.y, s2); \
        s2 = fmaf(W2.z, HV.z, s2); s2 = fmaf(W2.w, HV.w, s2); \
        s3 = fmaf(W3.x, HV.x, s3); s3 = fmaf(W3.y, HV.y, s3); \
        s3 = fmaf(W3.z, HV.z, s3); s3 = fmaf(W3.w, HV.w, s3);
        ACC(w00, w10, w20, w30, h0v)
        ACC(w01, w11, w21, w31, h1v)
        ACC(w02, w12, w22, w32, h2v)
        ACC(w03, w13, w23, w33, h3v)
#undef ACC

        // Value-halving butterfly over the 8 chunk lanes (4 swizzles).
        const bool b0 = (c & 1), b1 = (c & 2);
        // stage 1 (xor 1): keep 2 values
        float sa = b0 ? s0 : s2, sb = b0 ? s1 : s3;         // values we send
        float t0 = (b0 ? s2 : s0) + swz<XOR1>(sa);
        float t1 = (b0 ? s3 : s1) + swz<XOR1>(sb);
        // stage 2 (xor 2): keep 1 value
        float sc = b1 ? t0 : t1;
        float u  = (b1 ? t1 : t0) + swz<XOR2>(sc);
        // stage 3 (xor 4): full sum of row 4g+rsel on lanes c and c^4
        float sv = u + swz<XOR4>(u);
        sv += tab_cur;

        float v, sp = 0.f;
        if (f == 0) {
            // tanh(sv) = 1 - 2/(exp(2sv)+1)
            const float e2 = __expf(2.f * sv);
            v = 1.f - __fdividef(2.f, e2 + 1.f);
        } else {
            // softplus10 + decay factor
            const float z  = 10.f * sv;
            const float em = __expf(-fabsf(z));
            sp = 0.1f * (fmaxf(z, 0.f) + __logf(1.f + em));
            v  = __expf(-sp * dtv);
        }
        const float cross = swz<XOR8>(v);   // swap hidden <-> decay-factor
        const float hnew  = v * cross;

        if (c < 4) {
            const size_t ofs = (size_t)t * (BAT * HD) + (size_t)b * HD + row;
            if (f == 0) {
                o_hid[ofs] = v;
                o_hti[ofs] = hnew;
                hpad[p ^ 1][row >> 4][row & 15] = hnew;
            } else {
                o_dec[ofs] = sp;
            }
        }

        tab_cur = tab_nxt;
        tab_nxt = tab_pf;
        __syncthreads();
        p ^= 1;
    }
}

extern "C" void kernel_launch(void* const* d_in, const int* in_sizes, int n_in,
                              void* d_out, int out_size, void* d_ws, size_t ws_size,
                              hipStream_t stream) {
    const float* dt        = (const float*)d_in[0];
    const float* h0        = (const float*)d_in[1];
    const float* embed_W   = (const float*)d_in[2];
    const float* W_ih      = (const float*)d_in[3];
    const float* b_ih      = (const float*)d_in[4];
    const float* W_hh      = (const float*)d_in[5];
    const float* b_hh      = (const float*)d_in[6];
    const float* dec_W     = (const float*)d_in[7];
    const float* dec_b     = (const float*)d_in[8];
    const int*   seq_types = (const int*)  d_in[9];
    float* out  = (float*)d_out;

    float* tabH = (float*)d_ws;                 // [65][128]
    float* tabD = tabH + (KD + 1) * HD;         // [65][128]

    precompute_tables<<<KD + 1, 128, 0, stream>>>(embed_W, W_ih, b_ih, b_hh,
                                                  dec_W, dec_b, tabH, tabD);
    hawkes_rnn<<<BAT, 512, 0, stream>>>(dt, h0, W_hh, dec_W, seq_types,
                                        tabH, tabD, out);
}

// Round 5
// 1244.891 us; speedup vs baseline: 2.2845x; 1.0520x over previous
//
#include <hip/hip_runtime.h>

// Problem constants (match reference)
#define SEQ 2048
#define BAT 256
#define KD  64
#define HD  128
#define PADW 24   // 16 payload floats + 8 pad -> chunk stride 96B

// ds_swizzle xor patterns (BitMode: (xor<<10)|(or<<5)|and, and=0x1F)
template<int PAT>
__device__ __forceinline__ float swz(float x) {
    return __int_as_float(__builtin_amdgcn_ds_swizzle(__float_as_int(x), PAT));
}
#define XOR4 0x101F
#define XOR8 0x201F

// DPP quad-perm add: keep + (send pulled from partner lane). VALU-pipe, no
// LDS hop. CTRL 0xB1 = quad_perm(1,0,3,2) = xor1; 0x4E = quad_perm(2,3,0,1)
// = xor2.
template<int CTRL>
__device__ __forceinline__ float dpp_add(float keep, float send) {
    const int r = __builtin_amdgcn_update_dpp(0, __float_as_int(send),
                                              CTRL, 0xF, 0xF, true);
    return keep + __int_as_float(r);
}

// Pin a scalar float into a register: load can't sink past the volatile asm,
// value becomes opaque so it stays resident across the loop.
#define PIN(x) asm volatile("" : "+v"(x))
#define PIN4(v4) PIN(v4.x); PIN(v4.y); PIN(v4.z); PIN(v4.w)

// Step barrier: LDS visibility only. Deliberately does NOT drain vmcnt —
// the per-step global stores need no ordering with the barrier, and
// __syncthreads()'s implicit vmcnt(0) was serializing ~2048 store-ack waits.
#define STEP_BARRIER() do {                                   \
    asm volatile("s_waitcnt lgkmcnt(0)" ::: "memory");        \
    __builtin_amdgcn_s_barrier();                             \
    asm volatile("" ::: "memory");                            \
} while (0)

// ---------------------------------------------------------------------------
// Kernel 1: precompute type-dependent tables into d_ws.
//   tabH[ty][r] = sum_k embed_W[ty][k]*W_ih[r][k] + b_ih[r] + b_hh[r]
//   tabD[ty][r] = sum_k embed_W[ty][k]*dec_W[r][k] + dec_b[r]
// ---------------------------------------------------------------------------
__global__ __launch_bounds__(128) void precompute_tables(
    const float* __restrict__ embed_W, const float* __restrict__ W_ih,
    const float* __restrict__ b_ih,    const float* __restrict__ b_hh,
    const float* __restrict__ dec_W,   const float* __restrict__ dec_b,
    float* __restrict__ tabH, float* __restrict__ tabD)
{
    __shared__ float x[KD];
    const int ty = blockIdx.x;   // 0..64 (row 64 = padding, embed row is zero)
    const int r  = threadIdx.x;  // 0..127
    if (r < KD) x[r] = embed_W[ty * KD + r];
    __syncthreads();
    float ah = 0.f, ad = 0.f;
#pragma unroll
    for (int k = 0; k < KD; ++k) {
        const float xv = x[k];
        ah += xv * W_ih[r * KD + k];
        ad += xv * dec_W[r * (KD + HD) + k];
    }
    tabH[ty * HD + r] = ah + b_ih[r] + b_hh[r];
    tabD[ty * HD + r] = ad + dec_b[r];
}

// ---------------------------------------------------------------------------
// Kernel 2: persistent per-batch-element recurrence. One workgroup per batch
// element, 512 threads = 8 waves. Thread decomposition per step:
//   c = tid & 7        : column chunk (16 h-values each, 4x ds_read_b128)
//   f = (tid>>3) & 1   : 0 = hidden matvec (W_hh), 1 = decay matvec (dec_W)
//   g = tid >> 4       : row group (4 consecutive output rows)
// Each lane holds its 4x16 weight block in 16 float4 registers (pinned).
// Reduction over the 8 chunk lanes: xor1/xor2 via DPP (VALU), xor4 via
// ds_swizzle; hidden<->decay exchange via ds_swizzle xor8.
// h double-buffered in padded LDS; ONE lgkm-only barrier per step.
// ---------------------------------------------------------------------------
__global__ __launch_bounds__(512, 2) void hawkes_rnn(
    const float* __restrict__ dt_g,  const float* __restrict__ h0,
    const float* __restrict__ W_hh,  const float* __restrict__ dec_W,
    const int*   __restrict__ seq_types,
    const float* __restrict__ tabH,  const float* __restrict__ tabD,
    float* __restrict__ out)
{
    __shared__ __align__(16) float hpad[2][8][PADW];
    __shared__ float dts[SEQ];
    __shared__ int   tys[SEQ];

    const int b   = blockIdx.x;
    const int tid = threadIdx.x;
    const int c   = tid & 7;          // chunk
    const int f   = (tid >> 3) & 1;   // function
    const int g   = tid >> 4;         // row group, 0..31
    const int rsel = ((c & 1) << 1) | ((c >> 1) & 1);  // bit-swap from butterfly
    const int row  = 4 * g + rsel;    // the row this lane finalizes (c>=4 dup)

    // Stage dt / seq_types columns for this batch element.
    for (int t = tid; t < SEQ; t += 512) {
        dts[t] = dt_g[(size_t)t * BAT + b];
        tys[t] = seq_types[(size_t)t * BAT + b];
    }
    if (tid < HD) hpad[0][tid >> 4][tid & 15] = h0[b * HD + tid];

    // Load this lane's 4x16 weight block into NAMED registers and pin them.
    const float* wbase = f ? (dec_W + KD + (size_t)(4 * g) * (KD + HD) + c * 16)
                           : (W_hh  +      (size_t)(4 * g) * HD        + c * 16);
    const size_t wstr = f ? (KD + HD) : HD;
    float4 w00 = *reinterpret_cast<const float4*>(wbase + 0 * wstr + 0);
    float4 w01 = *reinterpret_cast<const float4*>(wbase + 0 * wstr + 4);
    float4 w02 = *reinterpret_cast<const float4*>(wbase + 0 * wstr + 8);
    float4 w03 = *reinterpret_cast<const float4*>(wbase + 0 * wstr + 12);
    float4 w10 = *reinterpret_cast<const float4*>(wbase + 1 * wstr + 0);
    float4 w11 = *reinterpret_cast<const float4*>(wbase + 1 * wstr + 4);
    float4 w12 = *reinterpret_cast<const float4*>(wbase + 1 * wstr + 8);
    float4 w13 = *reinterpret_cast<const float4*>(wbase + 1 * wstr + 12);
    float4 w20 = *reinterpret_cast<const float4*>(wbase + 2 * wstr + 0);
    float4 w21 = *reinterpret_cast<const float4*>(wbase + 2 * wstr + 4);
    float4 w22 = *reinterpret_cast<const float4*>(wbase + 2 * wstr + 8);
    float4 w23 = *reinterpret_cast<const float4*>(wbase + 2 * wstr + 12);
    float4 w30 = *reinterpret_cast<const float4*>(wbase + 3 * wstr + 0);
    float4 w31 = *reinterpret_cast<const float4*>(wbase + 3 * wstr + 4);
    float4 w32 = *reinterpret_cast<const float4*>(wbase + 3 * wstr + 8);
    float4 w33 = *reinterpret_cast<const float4*>(wbase + 3 * wstr + 12);
    PIN4(w00); PIN4(w01); PIN4(w02); PIN4(w03);
    PIN4(w10); PIN4(w11); PIN4(w12); PIN4(w13);
    PIN4(w20); PIN4(w21); PIN4(w22); PIN4(w23);
    PIN4(w30); PIN4(w31); PIN4(w32); PIN4(w33);

    const float* tabp = (f ? tabD : tabH) + row;

    __syncthreads();   // full barrier once: staging + weight loads complete

    // Strength-reduced output pointers (advance by BAT*HD per step).
    const size_t base = (size_t)b * HD + row;
    float* hid_p = out + base;
    float* dec_p = out + (size_t)SEQ * BAT * HD + base;
    float* hti_p = out + (size_t)2 * SEQ * BAT * HD + base;

    // Table prefetch pipeline (2 steps ahead; tables are L2-resident).
    float tab_cur = tabp[tys[0] * HD];
    float tab_nxt = tabp[tys[1] * HD];
    int p = 0;

    for (int t = 0; t < SEQ; ++t) {
        const int   tpf    = (t + 2 < SEQ) ? tys[t + 2] : 0;
        const float tab_pf = tabp[tpf * HD];   // issue now, use at t+2
        const float dtv    = dts[t];
        const float* hb    = &hpad[p][c][0];

        const float4 h0v = *reinterpret_cast<const float4*>(hb + 0);
        const float4 h1v = *reinterpret_cast<const float4*>(hb + 4);
        const float4 h2v = *reinterpret_cast<const float4*>(hb + 8);
        const float4 h3v = *reinterpret_cast<const float4*>(hb + 12);

        float s0 = 0.f, s1 = 0.f, s2 = 0.f, s3 = 0.f;
#define ACC(W0,W1,W2,W3,HV) \
        s0 = fmaf(W0.x, HV.x, s0); s0 = fmaf(W0.y, HV.y, s0); \
        s0 = fmaf(W0.z, HV.z, s0); s0 = fmaf(W0.w, HV.w, s0); \
        s1 = fmaf(W1.x, HV.x, s1); s1 = fmaf(W1.y, HV.y, s1); \
        s1 = fmaf(W1.z, HV.z, s1); s1 = fmaf(W1.w, HV.w, s1); \
        s2 = fmaf(W2.x, HV.x, s2); s2 = fmaf(W2.y, HV.y, s2); \
        s2 = fmaf(W2.z, HV.z, s2); s2 = fmaf(W2.w, HV.w, s2); \
        s3 = fmaf(W3.x, HV.x, s3); s3 = fmaf(W3.y, HV.y, s3); \
        s3 = fmaf(W3.z, HV.z, s3); s3 = fmaf(W3.w, HV.w, s3);
        ACC(w00, w10, w20, w30, h0v)
        ACC(w01, w11, w21, w31, h1v)
        ACC(w02, w12, w22, w32, h2v)
        ACC(w03, w13, w23, w33, h3v)
#undef ACC

        // Butterfly over the 8 chunk lanes: xor1/xor2 on VALU via DPP,
        // xor4 via ds_swizzle.
        const bool b0 = (c & 1), b1 = (c & 2);
        float t0 = dpp_add<0xB1>(b0 ? s2 : s0, b0 ? s0 : s2);
        float t1 = dpp_add<0xB1>(b0 ? s3 : s1, b0 ? s1 : s3);
        float u  = dpp_add<0x4E>(b1 ? t1 : t0, b1 ? t0 : t1);
        float sv = u + swz<XOR4>(u);
        sv += tab_cur;

        float v, sp = 0.f;
        if (f == 0) {
            // tanh(sv) = 1 - 2/(exp(2sv)+1)
            const float e2 = __expf(2.f * sv);
            v = 1.f - __fdividef(2.f, e2 + 1.f);
        } else {
            // softplus10 + decay factor
            const float z  = 10.f * sv;
            const float em = __expf(-fabsf(z));
            sp = 0.1f * (fmaxf(z, 0.f) + __logf(1.f + em));
            v  = __expf(-sp * dtv);
        }
        const float cross = swz<XOR8>(v);   // swap hidden <-> decay-factor
        const float hnew  = v * cross;

        if (c < 4) {
            if (f == 0) {
                hpad[p ^ 1][row >> 4][row & 15] = hnew;
                hid_p[0] = v;
                hti_p[0] = hnew;
            } else {
                dec_p[0] = sp;
            }
        }
        hid_p += BAT * HD; hti_p += BAT * HD; dec_p += BAT * HD;

        tab_cur = tab_nxt;
        tab_nxt = tab_pf;
        STEP_BARRIER();   // lgkm-only: h(t+1) visible, stores stay in flight
        p ^= 1;
    }
}

extern "C" void kernel_launch(void* const* d_in, const int* in_sizes, int n_in,
                              void* d_out, int out_size, void* d_ws, size_t ws_size,
                              hipStream_t stream) {
    const float* dt        = (const float*)d_in[0];
    const float* h0        = (const float*)d_in[1];
    const float* embed_W   = (const float*)d_in[2];
    const float* W_ih      = (const float*)d_in[3];
    const float* b_ih      = (const float*)d_in[4];
    const float* W_hh      = (const float*)d_in[5];
    const float* b_hh      = (const float*)d_in[6];
    const float* dec_W     = (const float*)d_in[7];
    const float* dec_b     = (const float*)d_in[8];
    const int*   seq_types = (const int*)  d_in[9];
    float* out  = (float*)d_out;

    float* tabH = (float*)d_ws;                 // [65][128]
    float* tabD = tabH + (KD + 1) * HD;         // [65][128]

    precompute_tables<<<KD + 1, 128, 0, stream>>>(embed_W, W_ih, b_ih, b_hh,
                                                  dec_W, dec_b, tabH, tabD);
    hawkes_rnn<<<BAT, 512, 0, stream>>>(dt, h0, W_hh, dec_W, seq_types,
                                        tabH, tabD, out);
}